// Round 10
// baseline (210.696 us; speedup 1.0000x reference)
//
#include <hip/hip_runtime.h>

// Interface (pinned): inputs fp32, mask int32, OUTPUT fp32.
// R10: structural consolidation, 7 launches -> 4.
//   - gemm_proj z=2 writes V^T (vtg) directly via packed u16x4 stores
//     (kills transpose_v + vb buffer).
//   - mega_mlp fuses LN1 + (X@Wo + bo) + ReLU + residual + LN2 -> d_out
//     (kills 2 ln_kernels + gemm_mlp + O1b/O1f/Uf buffers). Residual in
//     bf16 (error ~0.01, within 0.102 budget).
//   - attn_kernel = R9 verbatim (verified, absmax .03125).
// WS: wt[0,2) qb[2,10) kb[10,18) vtg[18,26) Of[26,42)  (peak 42 MiB)

typedef float f32x4 __attribute__((ext_vector_type(4)));
typedef short bf16x8 __attribute__((ext_vector_type(8)));
typedef unsigned short u16;
typedef unsigned short u16x4 __attribute__((ext_vector_type(4)));

#define MFMA16 __builtin_amdgcn_mfma_f32_16x16x32_bf16

__device__ __forceinline__ float bf2f(u16 u){
    unsigned x = ((unsigned)u) << 16;
    return __builtin_bit_cast(float, x);
}
__device__ __forceinline__ u16 f2bf(float f){  // round-to-nearest-even
    unsigned u = __builtin_bit_cast(unsigned, f);
    u = u + 0x7fffu + ((u >> 16) & 1u);
    return (u16)(u >> 16);
}

// ---------------------------------------------------------------------------
// Transpose + fp32->bf16 the 4 weight matrices (512x512).
// ---------------------------------------------------------------------------
__global__ __launch_bounds__(256) void transpose_w(
    const float* __restrict__ Wq, const float* __restrict__ Wk,
    const float* __restrict__ Wv, const float* __restrict__ Wo,
    u16* __restrict__ wt)
{
    const int z = blockIdx.z;
    const float* W = (z == 0) ? Wq : (z == 1) ? Wk : (z == 2) ? Wv : Wo;
    u16* out = wt + (size_t)z * 512 * 512;

    __shared__ u16 tile[32][33];
    const int k0 = blockIdx.y * 32, n0 = blockIdx.x * 32;
    const int c = threadIdx.x & 31, r = threadIdx.x >> 5;
#pragma unroll
    for (int i = 0; i < 4; i++) {
        int rr = r + i * 8;
        tile[rr][c] = f2bf(W[(size_t)(k0 + rr) * 512 + n0 + c]);
    }
    __syncthreads();
#pragma unroll
    for (int i = 0; i < 4; i++) {
        int rr = r + i * 8;
        out[(size_t)(n0 + rr) * 512 + k0 + c] = tile[c][rr];
    }
}

// ---------------------------------------------------------------------------
// Projection GEMM (verified R5 core): C = X(fp32) @ W(bf16^T) + bias.
// z=0: Q@Wq -> qb (row-major bf16). z=1: K@Wk -> kb. z=2: K@Wv -> vtg
// DIRECTLY in transposed layout [(b*8+h)*64+d][1024 keys]: per (mi,ni) the
// lane's 4 r-values are consecutive keys -> one packed u16x4 (8B) store.
// ---------------------------------------------------------------------------
__global__ __launch_bounds__(256) void gemm_proj(
    const float* __restrict__ Q, const float* __restrict__ K,
    const u16* __restrict__ wt,
    const float* __restrict__ bq, const float* __restrict__ bk, const float* __restrict__ bv,
    u16* __restrict__ qb, u16* __restrict__ kb, u16* __restrict__ vtg)
{
    __shared__ __align__(16) u16 lds_a[128 * 40];
    __shared__ __align__(16) u16 lds_b[128 * 40];

    const int z = blockIdx.z;
    const float* X = (z == 0) ? Q : K;
    const u16* Wt = wt + (size_t)z * 512 * 512;
    const float* bias = (z == 0) ? bq : (z == 1) ? bk : bv;

    const int bm = blockIdx.y, bn = blockIdx.x;
    const int t = threadIdx.x;
    const int wave = t >> 6, lane = t & 63, quad = lane >> 4, lm = lane & 15;
    const int wm = wave >> 1, wn = wave & 1;

    f32x4 acc[4][4];
    const f32x4 zz = {0.f, 0.f, 0.f, 0.f};
#pragma unroll
    for (int i = 0; i < 4; i++)
#pragma unroll
        for (int j = 0; j < 4; j++) acc[i][j] = zz;

    for (int k0 = 0; k0 < 512; k0 += 32) {
#pragma unroll
        for (int i = 0; i < 2; i++) {
            int idx = t + i * 256;
            int r = idx >> 2, c = (idx & 3) * 8;
            const float* xp = &X[(size_t)(bm * 128 + r) * 512 + k0 + c];
            f32x4 a0 = *(const f32x4*)xp;
            f32x4 a1 = *(const f32x4*)(xp + 4);
            bf16x8 xv;
#pragma unroll
            for (int j = 0; j < 4; j++) { xv[j] = (short)f2bf(a0[j]); xv[4 + j] = (short)f2bf(a1[j]); }
            *(bf16x8*)&lds_a[r * 40 + c] = xv;
            *(bf16x8*)&lds_b[r * 40 + c] =
                *(const bf16x8*)&Wt[(size_t)(bn * 128 + r) * 512 + k0 + c];
        }
        __syncthreads();
        bf16x8 af[4], bfr[4];
#pragma unroll
        for (int mi = 0; mi < 4; mi++)
            af[mi] = *(const bf16x8*)&lds_a[(wm * 64 + mi * 16 + lm) * 40 + quad * 8];
#pragma unroll
        for (int ni = 0; ni < 4; ni++)
            bfr[ni] = *(const bf16x8*)&lds_b[(wn * 64 + ni * 16 + lm) * 40 + quad * 8];
#pragma unroll
        for (int mi = 0; mi < 4; mi++)
#pragma unroll
            for (int ni = 0; ni < 4; ni++)
                acc[mi][ni] = MFMA16(af[mi], bfr[ni], acc[mi][ni], 0, 0, 0);
        __syncthreads();
    }

    if (z < 2) {
        u16* outb = (z == 0) ? qb : kb;
#pragma unroll
        for (int mi = 0; mi < 4; mi++) {
#pragma unroll
            for (int ni = 0; ni < 4; ni++) {
                const int col = bn * 128 + wn * 64 + ni * 16 + lm;
                const float bv_ = bias[col];
#pragma unroll
                for (int r = 0; r < 4; r++) {
                    const int row = bm * 128 + wm * 64 + mi * 16 + quad * 4 + r;
                    outb[(size_t)row * 512 + col] = f2bf(acc[mi][ni][r] + bv_);
                }
            }
        }
    } else {
        // V^T write: row = b*1024 + key, col = h*64 + d
        const int b = bm >> 3;
        const int key0 = (bm & 7) * 128 + wm * 64;
#pragma unroll
        for (int mi = 0; mi < 4; mi++) {
#pragma unroll
            for (int ni = 0; ni < 4; ni++) {
                const int col = bn * 128 + wn * 64 + ni * 16 + lm;
                const float bv_ = bias[col];
                const int h = col >> 6, d = col & 63;
                const int key = key0 + mi * 16 + quad * 4;
                u16x4 pk;
#pragma unroll
                for (int r = 0; r < 4; r++) pk[r] = f2bf(acc[mi][ni][r] + bv_);
                *(u16x4*)&vtg[(size_t)((b * 8 + h) * 64 + d) * 1024 + key] = pk;
            }
        }
    }
}

// ---------------------------------------------------------------------------
// Attention (R9 verbatim, verified): 128q/64key tiles, no-max softmax,
// RNE-bf16 P via per-wave LDS, XCD-swizzled grid.
// ---------------------------------------------------------------------------
__global__ __launch_bounds__(256) void attn_kernel(
    const u16* __restrict__ qb, const u16* __restrict__ kb, const u16* __restrict__ vtg,
    const int* __restrict__ mask, float* __restrict__ O)
{
    __shared__ __align__(16) u16 k_tile[64 * 88];
    __shared__ __align__(16) u16 vt[64 * 88];
    __shared__ __align__(16) u16 p_st[4 * 32 * 88];
    __shared__ float mskf[1024];

    const int i = blockIdx.x;
    const int s_ = i >> 3;
    const int bh = (i & 7) + 8 * (s_ >> 3);
    const int qt = s_ & 7;
    const int b = bh >> 3, h = bh & 7;

    const int t = threadIdx.x, wave = t >> 6, lane = t & 63;
    const int quad = lane >> 4, lm = lane & 15;
    const int qbase = qt * 128 + wave * 32;
    const size_t baseb = (size_t)b * 1024 * 512;
    const size_t vbase = (size_t)((b * 8 + h) * 64) * 1024;

#pragma unroll
    for (int ii = 0; ii < 4; ii++) {
        int j = t + ii * 256;
        mskf[j] = mask[b * 1024 + j] ? 1.0f : 0.0f;
    }

    bf16x8 aq[2][2];
#pragma unroll
    for (int m = 0; m < 2; m++)
#pragma unroll
        for (int ks = 0; ks < 2; ks++)
            aq[m][ks] = *(const bf16x8*)&qb[baseb +
                (size_t)(qbase + m * 16 + lm) * 512 + h * 64 + ks * 32 + quad * 8];

    float lsum[2][4];
    f32x4 oacc[2][4];
    const f32x4 zz = {0.f, 0.f, 0.f, 0.f};
#pragma unroll
    for (int m = 0; m < 2; m++) {
#pragma unroll
        for (int r = 0; r < 4; r++) lsum[m][r] = 0.f;
#pragma unroll
        for (int c = 0; c < 4; c++) oacc[m][c] = zz;
    }

    const float SC2 = 0.125f * 1.44269504088896341f;
    const int srow = t >> 2, scol = (t & 3) * 16;
    u16* pw = &p_st[wave * 32 * 88];

    for (int kt = 0; kt < 16; ++kt) {
        const int keyg = kt * 64;
        {
            const u16* kp = &kb[baseb + (size_t)(keyg + srow) * 512 + h * 64 + scol];
            *(bf16x8*)&k_tile[srow * 88 + scol]     = *(const bf16x8*)kp;
            *(bf16x8*)&k_tile[srow * 88 + scol + 8] = *(const bf16x8*)(kp + 8);
            const u16* vp = &vtg[vbase + (size_t)srow * 1024 + keyg + scol];
            *(bf16x8*)&vt[srow * 88 + scol]     = *(const bf16x8*)vp;
            *(bf16x8*)&vt[srow * 88 + scol + 8] = *(const bf16x8*)(vp + 8);
        }
        __syncthreads();

        bf16x8 bk[4][2];
#pragma unroll
        for (int n = 0; n < 4; n++)
#pragma unroll
            for (int ks = 0; ks < 2; ks++)
                bk[n][ks] = *(const bf16x8*)&k_tile[(n * 16 + lm) * 88 + ks * 32 + quad * 8];

#pragma unroll
        for (int m = 0; m < 2; m++) {
#pragma unroll
            for (int n = 0; n < 4; n++) {
                f32x4 S = zz;
                S = MFMA16(aq[m][0], bk[n][0], S, 0, 0, 0);
                S = MFMA16(aq[m][1], bk[n][1], S, 0, 0, 0);
                const float mf = mskf[keyg + n * 16 + lm];
#pragma unroll
                for (int r = 0; r < 4; r++) {
                    float p = __builtin_amdgcn_exp2f(S[r] * SC2) * mf;
                    lsum[m][r] += p;
                    pw[(m * 16 + quad * 4 + r) * 88 + n * 16 + lm] = f2bf(p);
                }
            }
        }

#pragma unroll
        for (int m = 0; m < 2; m++) {
#pragma unroll
            for (int ks = 0; ks < 2; ks++) {
                bf16x8 ap = *(const bf16x8*)&pw[(m * 16 + lm) * 88 + ks * 32 + quad * 8];
#pragma unroll
                for (int c = 0; c < 4; c++) {
                    bf16x8 bv_ = *(const bf16x8*)&vt[(c * 16 + lm) * 88 + ks * 32 + quad * 8];
                    oacc[m][c] = MFMA16(ap, bv_, oacc[m][c], 0, 0, 0);
                }
            }
        }
        __syncthreads();
    }

#pragma unroll
    for (int m = 0; m < 2; m++)
#pragma unroll
        for (int r = 0; r < 4; r++) {
            float s = lsum[m][r];
            s += __shfl_xor(s, 1); s += __shfl_xor(s, 2);
            s += __shfl_xor(s, 4); s += __shfl_xor(s, 8);
            lsum[m][r] = s;
        }

#pragma unroll
    for (int m = 0; m < 2; m++)
#pragma unroll
        for (int c = 0; c < 4; c++)
#pragma unroll
            for (int r = 0; r < 4; r++) {
                const int row = qbase + m * 16 + quad * 4 + r;
                const int d = h * 64 + c * 16 + lm;
                const size_t off = baseb + (size_t)row * 512 + d;
                O[off] = bf2f(qb[off]) + oacc[m][c][r] / lsum[m][r];
            }
}

// ---------------------------------------------------------------------------
// Mega MLP: per block = 32 full rows.
//   Phase A: LN1(Of rows) -> lnA bf16 in LDS (stride 536: conflict-free).
//   Phase B: acc = lnA @ Wo^T (wave w owns cols [128w,128w+128), 2x8 tiles).
//   Phase C: y = lnA + relu(acc + bo); LN2 via lm-shuffle + cross-wave LDS
//            reduce; out = (y-mu)*rs*g1 + b1  (fp32 d_out).
// ---------------------------------------------------------------------------
__global__ __launch_bounds__(256) void mega_mlp(
    const float* __restrict__ Of, const u16* __restrict__ wt,
    const float* __restrict__ bo,
    const float* __restrict__ g0, const float* __restrict__ b0,
    const float* __restrict__ g1, const float* __restrict__ b1,
    float* __restrict__ out)
{
    __shared__ __align__(16) u16 lnA[32 * 536];
    __shared__ __align__(16) u16 Bs[512 * 40];
    __shared__ float ws_s[4][32];
    __shared__ float ws_q[4][32];

    const u16* Wt = wt + (size_t)3 * 512 * 512;
    const int bm = blockIdx.x;
    const int t = threadIdx.x, wave = t >> 6, lane = t & 63;
    const int quad = lane >> 4, lm = lane & 15;
    const size_t rowbase = (size_t)bm * 32;

    // ---- Phase A: LN1 of 32 rows (8 threads/row, 64 elems each) ----
    {
        const int r = t >> 3, c0 = (t & 7) * 64;
        const float* x = &Of[(rowbase + r) * 512 + c0];
        float v[64];
#pragma unroll
        for (int j = 0; j < 16; j++) *(f32x4*)&v[j * 4] = *(const f32x4*)&x[j * 4];
        float s = 0.f, sq = 0.f;
#pragma unroll
        for (int j = 0; j < 64; j++) { s += v[j]; sq += v[j] * v[j]; }
        s += __shfl_xor(s, 1); sq += __shfl_xor(sq, 1);
        s += __shfl_xor(s, 2); sq += __shfl_xor(sq, 2);
        s += __shfl_xor(s, 4); sq += __shfl_xor(sq, 4);
        const float mu = s * (1.f / 512.f);
        const float var = sq * (1.f / 512.f) - mu * mu;
        const float rs = rsqrtf(var + 1e-5f);
#pragma unroll
        for (int j0 = 0; j0 < 64; j0 += 8) {
            bf16x8 ov;
#pragma unroll
            for (int j = 0; j < 8; j++) {
                const int col = c0 + j0 + j;
                ov[j] = (short)f2bf((v[j0 + j] - mu) * rs * g0[col] + b0[col]);
            }
            *(bf16x8*)&lnA[r * 536 + c0 + j0] = ov;
        }
    }
    __syncthreads();

    // ---- Phase B: GEMM (acc[mi=2][ni=8], wave cols = [128*wave, +128)) ----
    f32x4 acc[2][8];
    const f32x4 zz = {0.f, 0.f, 0.f, 0.f};
#pragma unroll
    for (int mi = 0; mi < 2; mi++)
#pragma unroll
        for (int ni = 0; ni < 8; ni++) acc[mi][ni] = zz;

    for (int k0 = 0; k0 < 512; k0 += 32) {
#pragma unroll
        for (int i = 0; i < 8; i++) {
            int idx = t + i * 256;
            int row = idx >> 2, kc = (idx & 3) * 8;
            *(bf16x8*)&Bs[row * 40 + kc] =
                *(const bf16x8*)&Wt[(size_t)row * 512 + k0 + kc];
        }
        __syncthreads();
        bf16x8 af[2], bfr[8];
#pragma unroll
        for (int mi = 0; mi < 2; mi++)
            af[mi] = *(const bf16x8*)&lnA[(mi * 16 + lm) * 536 + k0 + quad * 8];
#pragma unroll
        for (int ni = 0; ni < 8; ni++)
            bfr[ni] = *(const bf16x8*)&Bs[(wave * 128 + ni * 16 + lm) * 40 + quad * 8];
#pragma unroll
        for (int mi = 0; mi < 2; mi++)
#pragma unroll
            for (int ni = 0; ni < 8; ni++)
                acc[mi][ni] = MFMA16(af[mi], bfr[ni], acc[mi][ni], 0, 0, 0);
        __syncthreads();
    }

    // ---- Phase C: bias + relu + residual, then LN2 ----
    float ps[2][4], pq[2][4];
#pragma unroll
    for (int mi = 0; mi < 2; mi++)
#pragma unroll
        for (int r = 0; r < 4; r++) { ps[mi][r] = 0.f; pq[mi][r] = 0.f; }

#pragma unroll
    for (int ni = 0; ni < 8; ni++) {
        const int col = wave * 128 + ni * 16 + lm;
        const float bov = bo[col];
#pragma unroll
        for (int mi = 0; mi < 2; mi++) {
#pragma unroll
            for (int r = 0; r < 4; r++) {
                const int row = mi * 16 + quad * 4 + r;
                const float resid = bf2f(lnA[row * 536 + col]);
                const float yy = resid + fmaxf(acc[mi][ni][r] + bov, 0.f);
                acc[mi][ni][r] = yy;  // reuse acc as y
                ps[mi][r] += yy;
                pq[mi][r] += yy * yy;
            }
        }
    }
    // reduce over the 16 lm lanes (same row within each quad)
#pragma unroll
    for (int mi = 0; mi < 2; mi++)
#pragma unroll
        for (int r = 0; r < 4; r++) {
            float s = ps[mi][r], q = pq[mi][r];
            s += __shfl_xor(s, 1); q += __shfl_xor(q, 1);
            s += __shfl_xor(s, 2); q += __shfl_xor(q, 2);
            s += __shfl_xor(s, 4); q += __shfl_xor(q, 4);
            s += __shfl_xor(s, 8); q += __shfl_xor(q, 8);
            ps[mi][r] = s; pq[mi][r] = q;
        }
    if (lm == 0) {
#pragma unroll
        for (int mi = 0; mi < 2; mi++)
#pragma unroll
            for (int r = 0; r < 4; r++) {
                const int row = mi * 16 + quad * 4 + r;
                ws_s[wave][row] = ps[mi][r];
                ws_q[wave][row] = pq[mi][r];
            }
    }
    __syncthreads();

    float murow[2][4], rsrow[2][4];
#pragma unroll
    for (int mi = 0; mi < 2; mi++)
#pragma unroll
        for (int r = 0; r < 4; r++) {
            const int row = mi * 16 + quad * 4 + r;
            const float S = ws_s[0][row] + ws_s[1][row] + ws_s[2][row] + ws_s[3][row];
            const float Q2 = ws_q[0][row] + ws_q[1][row] + ws_q[2][row] + ws_q[3][row];
            const float mu = S * (1.f / 512.f);
            const float var = Q2 * (1.f / 512.f) - mu * mu;
            murow[mi][r] = mu;
            rsrow[mi][r] = rsqrtf(var + 1e-5f);
        }

#pragma unroll
    for (int ni = 0; ni < 8; ni++) {
        const int col = wave * 128 + ni * 16 + lm;
        const float g1v = g1[col], b1v = b1[col];
#pragma unroll
        for (int mi = 0; mi < 2; mi++)
#pragma unroll
            for (int r = 0; r < 4; r++) {
                const int row = mi * 16 + quad * 4 + r;
                out[(rowbase + row) * 512 + col] =
                    (acc[mi][ni][r] - murow[mi][r]) * rsrow[mi][r] * g1v + b1v;
            }
    }
}

extern "C" void kernel_launch(void* const* d_in, const int* in_sizes, int n_in,
                              void* d_out, int out_size, void* d_ws, size_t ws_size,
                              hipStream_t stream) {
    const float* Q  = (const float*)d_in[0];
    const float* K  = (const float*)d_in[1];
    const int* mask = (const int*)d_in[2];
    const float* Wq = (const float*)d_in[3];
    const float* bq = (const float*)d_in[4];
    const float* Wk = (const float*)d_in[5];
    const float* bk = (const float*)d_in[6];
    const float* Wv = (const float*)d_in[7];
    const float* bv = (const float*)d_in[8];
    const float* Wo = (const float*)d_in[9];
    const float* bo = (const float*)d_in[10];
    const float* g0 = (const float*)d_in[11];
    const float* b0 = (const float*)d_in[12];
    const float* g1 = (const float*)d_in[13];
    const float* b1 = (const float*)d_in[14];
    float* out = (float*)d_out;

    char* ws = (char*)d_ws;
    const size_t MB = 1048576;
    u16*   wt  = (u16*)(ws);
    u16*   qb  = (u16*)(ws + 2 * MB);
    u16*   kb  = (u16*)(ws + 10 * MB);
    u16*   vtg = (u16*)(ws + 18 * MB);
    float* Of  = (float*)(ws + 26 * MB);

    transpose_w<<<dim3(16, 16, 4), 256, 0, stream>>>(Wq, Wk, Wv, Wo, wt);
    gemm_proj<<<dim3(4, 64, 3), 256, 0, stream>>>(Q, K, wt, bq, bk, bv, qb, kb, vtg);
    attn_kernel<<<512, 256, 0, stream>>>(qb, kb, vtg, mask, Of);
    mega_mlp<<<256, 256, 0, stream>>>(Of, wt, bo, g0, b0, g1, b1, out);
}